// Round 16
// baseline (99.448 us; speedup 1.0000x reference)
//
#include <hip/hip_runtime.h>
#include <math.h>

typedef _Float16 half2v __attribute__((ext_vector_type(2)));
typedef __fp16 fp16x2 __attribute__((ext_vector_type(2)));
typedef _Float16 half4 __attribute__((ext_vector_type(4)));
typedef _Float16 half8 __attribute__((ext_vector_type(8)));
typedef float floatx4 __attribute__((ext_vector_type(4)));

#define C_RADIUS 20.0f

// ---------------------------------------------------------------------------
// d_ws layout (units = _Float16). Fragments for mfma_f32_16x16x32_f16:
// lane l holds 8 elems: free-index = l&15, k = 8*(l>>4) + e  (e=0..7).
//   W1f [28 tn][64 lane][8]   @ 0       n=tn*16+(l&15); k==0->b1, k=1..17->w1[n][k-1], else 0
//   W2f [20 tn][13 ks][64][8] @ 14336   k=32ks+...; k<400->w2[n][k], k==400->b2[n], else 0
//   W3f [10 ks][64][8]        @ 147456  n=l&15 (<6); k<300->w3, k==300->b3
// ---------------------------------------------------------------------------

__global__ void actor_prep(const float* __restrict__ w1, const float* __restrict__ b1,
                           const float* __restrict__ w2, const float* __restrict__ b2,
                           const float* __restrict__ w3, const float* __restrict__ b3,
                           _Float16* __restrict__ ws) {
  int gid = blockIdx.x * 256 + threadIdx.x;
  if (gid >= 19072) return;
  half8 hv;
  _Float16* dst;
  if (gid < 1792) {  // W1f (bias-first layout)
    int l = gid & 63, tn = gid >> 6;
    int n = tn * 16 + (l & 15);
    int kc = 8 * (l >> 4);
#pragma unroll
    for (int e = 0; e < 8; ++e) {
      int k = kc + e;
      float v = 0.f;
      if (n < 400) {
        if (k == 0) v = b1[n];
        else if (k <= 17) v = w1[n * 17 + (k - 1)];
      }
      hv[e] = (_Float16)v;
    }
    dst = ws + gid * 8;
  } else if (gid < 1792 + 16640) {  // W2f
    int g = gid - 1792;
    int l = g & 63, t = g >> 6;     // t = tn*13 + ks
    int ks = t % 13, tn = t / 13;
    int n = tn * 16 + (l & 15);
    int kc = ks * 32 + 8 * (l >> 4);
#pragma unroll
    for (int e = 0; e < 8; ++e) {
      int k = kc + e;
      float v = 0.f;
      if (n < 300) {
        if (k < 400) v = w2[n * 400 + k];
        else if (k == 400) v = b2[n];
      }
      hv[e] = (_Float16)v;
    }
    dst = ws + 14336 + g * 8;
  } else {  // W3f
    int g = gid - 1792 - 16640;
    int l = g & 63, ks = g >> 6;
    int n = l & 15;
    int kc = ks * 32 + 8 * (l >> 4);
#pragma unroll
    for (int e = 0; e < 8; ++e) {
      int k = kc + e;
      float v = 0.f;
      if (n < 6) {
        if (k < 300) v = w3[n * 300 + k];
        else if (k == 300) v = b3[n];
      }
      hv[e] = (_Float16)v;
    }
    dst = ws + 147456 + g * 8;
  }
  *reinterpret_cast<half8*>(dst) = hv;
}

#define LD1 408   // a1 row stride; cols 0..399 = a1, col 400 = 1.0 (W2 k=400 b2 slot), 401..407 = 0
#define LD2 328   // a2 row stride; cols 0..299 = a2, 300 = 1.0 (b3 slot), 301..319 = 0

#define MFMA32(A, B, C) C = __builtin_amdgcn_mfma_f32_16x16x32_f16(A, B, C, 0, 0, 0)

__device__ __forceinline__ half4 pack4(float v0, float v1, float v2, float v3) {
  fp16x2 a = __builtin_amdgcn_cvt_pkrtz(v0, v1);
  fp16x2 b = __builtin_amdgcn_cvt_pkrtz(v2, v3);
  half2v a2 = __builtin_bit_cast(half2v, a);
  half2v b2 = __builtin_bit_cast(half2v, b);
  return __builtin_shufflevector(a2, b2, 0, 1, 2, 3);
}

// pack then packed-relu in f16 (RTZ commutes with relu)
__device__ __forceinline__ half4 pack4_relu(floatx4 v) {
  half4 hv = pack4(v[0], v[1], v[2], v[3]);
  return __builtin_elementwise_max(hv, (half4)(_Float16)0.0f);
}

__device__ __forceinline__ float fast_tanh(float x) {
  float e = __expf(2.0f * x);
  return 1.0f - 2.0f / (e + 1.0f);
}

__global__ __launch_bounds__(512, 6) void actor_fused(const float* __restrict__ state,
                                                      const _Float16* __restrict__ ws,
                                                      float* __restrict__ out) {
  // 52,256 B -> 3 blocks/CU (24 waves/CU), VGPR cap ~85 (incl. AGPR-held acc).
  __shared__ __align__(16) _Float16 aL[64 * LD1 + 16];

  const int tid = threadIdx.x;
  const int lane = tid & 63;
  const int w = tid >> 6;       // 8 waves
  const int r15 = lane & 15;
  const int c4 = lane >> 4;
  const int row0 = blockIdx.x * 64;

  // ---- stage 0 (NO barrier after — phase 1 doesn't touch these cols) ----
  // col 400 = 1.0 (b2 slot), 401..407 = 0; zero 16-elem tail pad
  {
    int r = tid >> 3, c = tid & 7;          // 64 rows x 8 cols
    aL[r * LD1 + 400 + c] = (c == 0) ? (_Float16)1.0f : (_Float16)0.0f;
  }
  if (tid < 16) aL[64 * LD1 + tid] = (_Float16)0.0f;

  // ---- build phase-1 S fragments DIRECTLY from global (no LDS staging) ----
  // S elem (c4, e): k = 8*c4+e.  k==0 -> 1.0 ; 1<=k<=17 -> state[k-1] ; else 0.
  half8 S[4];
#pragma unroll
  for (int m = 0; m < 4; ++m) {
    const float* sp = state + (size_t)(row0 + 16 * m + r15) * 17;
    half8 v = {};
    if (c4 == 0) {
      v[0] = (_Float16)1.0f;
#pragma unroll
      for (int e = 1; e < 8; ++e) v[e] = (_Float16)sp[e - 1];
    } else if (c4 == 1) {
#pragma unroll
      for (int e = 0; e < 8; ++e) v[e] = (_Float16)sp[7 + e];
    } else if (c4 == 2) {
      v[0] = (_Float16)sp[15];
      v[1] = (_Float16)sp[16];
    }
    S[m] = v;
  }

  // ---- phase 1: a1 = relu([1,state] @ [b1|W1]^T) ----
  {
    const half8* W1f = reinterpret_cast<const half8*>(ws);
#pragma unroll
    for (int t = 0; t < 4; ++t) {
      int tn = w + 8 * t;
      if (tn < 25) {
        half8 aW = W1f[tn * 64 + lane];
        floatx4 acc[4];
#pragma unroll
        for (int m = 0; m < 4; ++m) {
          acc[m] = (floatx4){0.f, 0.f, 0.f, 0.f};
          MFMA32(aW, S[m], acc[m]);
        }
        int n0 = tn * 16 + 4 * c4;   // < 400
#pragma unroll
        for (int m = 0; m < 4; ++m) {
          half4 hv = pack4_relu(acc[m]);
          *reinterpret_cast<half4*>(&aL[(16 * m + r15) * LD1 + n0]) = hv;
        }
      }
    }
  }
  __syncthreads();

  // ---- phase 2: a2 = relu(a1 @ W2^T + b2); n-tiles {3,3,3,3,2,2,2,2} ----
  {
    const half8* W2f = reinterpret_cast<const half8*>(ws + 14336);
    const int nt = (w < 4) ? 3 : 2;
    const int tn0 = (w < 4) ? (w * 3) : (12 + (w - 4) * 2);
    floatx4 acc[4][3];
#pragma unroll
    for (int m = 0; m < 4; ++m)
#pragma unroll
      for (int t = 0; t < 3; ++t) acc[m][t] = (floatx4){0.f, 0.f, 0.f, 0.f};

    half8 bA[3];
#pragma unroll
    for (int t = 0; t < 3; ++t)
      if (t < nt) bA[t] = W2f[((tn0 + t) * 13 + 0) * 64 + lane];

#pragma unroll 1
    for (int ks = 0; ks < 13; ++ks) {
      half8 F[4];
#pragma unroll
      for (int m = 0; m < 4; ++m)
        F[m] = *reinterpret_cast<const half8*>(&aL[(16 * m + r15) * LD1 + ks * 32 + 8 * c4]);
      __builtin_amdgcn_s_setprio(1);
#pragma unroll
      for (int t = 0; t < 3; ++t)
        if (t < nt)
#pragma unroll
          for (int m = 0; m < 4; ++m)
            MFMA32(bA[t], F[m], acc[m][t]);
      __builtin_amdgcn_s_setprio(0);
      if (ks < 12) {
#pragma unroll
        for (int t = 0; t < 3; ++t)
          if (t < nt) bA[t] = W2f[((tn0 + t) * 13 + ks + 1) * 64 + lane];
      }
    }

    __syncthreads();  // all a1 reads complete before aliased a2 writes

    // epilogue: packed relu; n==300 forced 1.0 (b3 slot); n 301..319 write 0
#pragma unroll
    for (int t = 0; t < 3; ++t)
      if (t < nt) {
        int n0 = (tn0 + t) * 16 + 4 * c4;
#pragma unroll
        for (int m = 0; m < 4; ++m) {
          half4 hv = pack4_relu(acc[m][t]);
          if (n0 == 300) hv[0] = (_Float16)1.0f;
          *reinterpret_cast<half4*>(&aL[(16 * m + r15) * LD2 + n0]) = hv;
        }
      }
  }
  __syncthreads();

  // ---- phase 3+4: z3 = a2 @ W3^T + b3 -> tanh -> projection -> store; waves 0..3 ----
  if (w < 4) {
    const half8* W3f = reinterpret_cast<const half8*>(ws + 147456);
    floatx4 za = (floatx4){0.f, 0.f, 0.f, 0.f};
    floatx4 zb = (floatx4){0.f, 0.f, 0.f, 0.f};
    const int row = 16 * w + r15;
#pragma unroll
    for (int ks = 0; ks < 10; ks += 2) {
      half8 F0 = *reinterpret_cast<const half8*>(&aL[row * LD2 + ks * 32 + 8 * c4]);
      half8 F1 = *reinterpret_cast<const half8*>(&aL[row * LD2 + (ks + 1) * 32 + 8 * c4]);
      MFMA32(W3f[ks * 64 + lane], F0, za);
      MFMA32(W3f[(ks + 1) * 64 + lane], F1, zb);
    }
    floatx4 z = za + zb;
    // lane(c4,r15) holds n = 4*c4+j for act-row = 16w+r15. Owners: c4==0 lanes.
    float v4 = __shfl(z[0], r15 + 16, 64);  // n=4 from lane (c4=1, r15)
    float v5 = __shfl(z[1], r15 + 16, 64);  // n=5
    if (c4 == 0) {
      const int grow = row0 + row;
      float q[6], wv[6], aq[6], wa[6];
      q[0] = fast_tanh(z[0]); q[1] = fast_tanh(z[1]);
      q[2] = fast_tanh(z[2]); q[3] = fast_tanh(z[3]);
      q[4] = fast_tanh(v4);   q[5] = fast_tanh(v5);
      float S2 = 0.f;
#pragma unroll
      for (int i = 0; i < 6; ++i) {
        wv[i] = fabsf(state[grow * 17 + 11 + i]);
        aq[i] = fabsf(q[i]);
        wa[i] = wv[i] * aq[i];
        S2 += wa[i];
      }
      float lam = 0.f;
      if (!(S2 <= C_RADIUS)) {
        float rr[6], w2s[6], was[6];
#pragma unroll
        for (int i = 0; i < 6; ++i) {
          rr[i] = (wv[i] > 0.f) ? (aq[i] / fmaxf(wv[i], 1e-30f)) : -__builtin_inff();
          w2s[i] = wv[i] * wv[i];
          was[i] = wa[i];
        }
#pragma unroll
        for (int p = 0; p < 5; ++p)
#pragma unroll
          for (int j2 = 0; j2 < 5; ++j2)
            if (j2 < 5 - p) {
              if (rr[j2] < rr[j2 + 1]) {
                float t0 = rr[j2];  rr[j2] = rr[j2 + 1];  rr[j2 + 1] = t0;
                float t1 = w2s[j2]; w2s[j2] = w2s[j2 + 1]; w2s[j2 + 1] = t1;
                float t2 = was[j2]; was[j2] = was[j2 + 1]; was[j2 + 1] = t2;
              }
            }
        float A = 0.f, Bc = 0.f;
        float lamk[6];
        int kc = 0;
#pragma unroll
        for (int i = 0; i < 6; ++i) {
          A += was[i];
          Bc += w2s[i];
          lamk[i] = (A - C_RADIUS) / fmaxf(Bc, 1e-30f);
          if (rr[i] > lamk[i]) ++kc;
        }
        int idx = kc - 1;
        if (idx < 0) idx = 0;
        float lsel = lamk[0];
#pragma unroll
        for (int i = 1; i < 6; ++i)
          if (i == idx) lsel = lamk[i];
        lam = fmaxf(lsel, 0.f);
      }
#pragma unroll
      for (int i = 0; i < 6; ++i) {
        float x = fmaxf(aq[i] - lam * wv[i], 0.f);
        out[grow * 6 + i] = copysignf(x, q[i]);
      }
    }
  }
}

extern "C" void kernel_launch(void* const* d_in, const int* in_sizes, int n_in,
                              void* d_out, int out_size, void* d_ws, size_t ws_size,
                              hipStream_t stream) {
  const float* state = (const float*)d_in[0];
  const float* w1 = (const float*)d_in[1];
  const float* b1 = (const float*)d_in[2];
  const float* w2 = (const float*)d_in[3];
  const float* b2 = (const float*)d_in[4];
  const float* w3 = (const float*)d_in[5];
  const float* b3 = (const float*)d_in[6];
  _Float16* ws = (_Float16*)d_ws;
  float* out = (float*)d_out;

  actor_prep<<<75, 256, 0, stream>>>(w1, b1, w2, b2, w3, b3, ws);
  actor_fused<<<4096, 512, 0, stream>>>(state, ws, out);
}

// Round 20
// 89.403 us; speedup vs baseline: 1.1124x; 1.1124x over previous
//
#include <hip/hip_runtime.h>
#include <math.h>

typedef _Float16 half2v __attribute__((ext_vector_type(2)));
typedef __fp16 fp16x2 __attribute__((ext_vector_type(2)));
typedef _Float16 half4 __attribute__((ext_vector_type(4)));
typedef _Float16 half8 __attribute__((ext_vector_type(8)));
typedef float floatx4 __attribute__((ext_vector_type(4)));

#define C_RADIUS 20.0f

// ---------------------------------------------------------------------------
// d_ws layout (units = _Float16). Fragments for mfma_f32_16x16x32_f16:
// lane l holds 8 elems: free-index = l&15, k = 8*(l>>4) + e  (e=0..7).
//   W1f [28 tn][64 lane][8]   @ 0       n=tn*16+(l&15); k==0->b1, k=1..17->w1[n][k-1], else 0
//   W2f [20 tn][13 ks][64][8] @ 14336   k=32ks+...; k<400->w2[n][k], k==400->b2[n], else 0
//   W3f [10 ks][64][8]        @ 147456  n=l&15 (<6); k<300->w3, k==300->b3
// ---------------------------------------------------------------------------

__global__ void actor_prep(const float* __restrict__ w1, const float* __restrict__ b1,
                           const float* __restrict__ w2, const float* __restrict__ b2,
                           const float* __restrict__ w3, const float* __restrict__ b3,
                           _Float16* __restrict__ ws) {
  int gid = blockIdx.x * 256 + threadIdx.x;
  if (gid >= 19072) return;
  half8 hv;
  _Float16* dst;
  if (gid < 1792) {  // W1f (bias-first layout)
    int l = gid & 63, tn = gid >> 6;
    int n = tn * 16 + (l & 15);
    int kc = 8 * (l >> 4);
#pragma unroll
    for (int e = 0; e < 8; ++e) {
      int k = kc + e;
      float v = 0.f;
      if (n < 400) {
        if (k == 0) v = b1[n];
        else if (k <= 17) v = w1[n * 17 + (k - 1)];
      }
      hv[e] = (_Float16)v;
    }
    dst = ws + gid * 8;
  } else if (gid < 1792 + 16640) {  // W2f
    int g = gid - 1792;
    int l = g & 63, t = g >> 6;     // t = tn*13 + ks
    int ks = t % 13, tn = t / 13;
    int n = tn * 16 + (l & 15);
    int kc = ks * 32 + 8 * (l >> 4);
#pragma unroll
    for (int e = 0; e < 8; ++e) {
      int k = kc + e;
      float v = 0.f;
      if (n < 300) {
        if (k < 400) v = w2[n * 400 + k];
        else if (k == 400) v = b2[n];
      }
      hv[e] = (_Float16)v;
    }
    dst = ws + 14336 + g * 8;
  } else {  // W3f
    int g = gid - 1792 - 16640;
    int l = g & 63, ks = g >> 6;
    int n = l & 15;
    int kc = ks * 32 + 8 * (l >> 4);
#pragma unroll
    for (int e = 0; e < 8; ++e) {
      int k = kc + e;
      float v = 0.f;
      if (n < 6) {
        if (k < 300) v = w3[n * 300 + k];
        else if (k == 300) v = b3[n];
      }
      hv[e] = (_Float16)v;
    }
    dst = ws + 147456 + g * 8;
  }
  *reinterpret_cast<half8*>(dst) = hv;
}

#define LD1 408   // a1 row stride; cols 0..399 = a1 (state staged here pre-phase-1),
                  // col 400 = 1.0 (W2 k=400 b2 slot), 401..407 = 0
#define LD2 328   // a2 row stride; cols 0..299 = a2, 300 = 1.0 (b3 slot), 301..319 = 0

#define MFMA32(A, B, C) C = __builtin_amdgcn_mfma_f32_16x16x32_f16(A, B, C, 0, 0, 0)

__device__ __forceinline__ half4 pack4(float v0, float v1, float v2, float v3) {
  fp16x2 a = __builtin_amdgcn_cvt_pkrtz(v0, v1);
  fp16x2 b = __builtin_amdgcn_cvt_pkrtz(v2, v3);
  half2v a2 = __builtin_bit_cast(half2v, a);
  half2v b2 = __builtin_bit_cast(half2v, b);
  return __builtin_shufflevector(a2, b2, 0, 1, 2, 3);
}

// pack then packed-relu in f16 (RTZ commutes with relu)
__device__ __forceinline__ half4 pack4_relu(floatx4 v) {
  half4 hv = pack4(v[0], v[1], v[2], v[3]);
  return __builtin_elementwise_max(hv, (half4)(_Float16)0.0f);
}

__device__ __forceinline__ float fast_tanh(float x) {
  float e = __expf(2.0f * x);
  return 1.0f - 2.0f / (e + 1.0f);
}

__global__ __launch_bounds__(512, 6) void actor_fused(const float* __restrict__ state,
                                                      const _Float16* __restrict__ ws,
                                                      float* __restrict__ out) {
  // 52,256 B -> 3 blocks/CU (24 waves/CU), VGPR cap ~85 (incl. AGPR-held acc).
  __shared__ __align__(16) _Float16 aL[64 * LD1 + 16];

  const int tid = threadIdx.x;
  const int lane = tid & 63;
  const int w = tid >> 6;       // 8 waves
  const int r15 = lane & 15;
  const int c4 = lane >> 4;
  const int row0 = blockIdx.x * 64;

  // ---- stage 0: state into a1 cols 0..31 (col0=1.0, 1..17=state, 18..31=0);
  //      col 400 = 1.0 (b2 slot), 401..407 = 0; zero 16-elem tail pad ----
  for (int i = tid; i < 2048; i += 512) {   // 64 rows x 32 cols
    int r = i >> 5, c = i & 31;
    float v = 0.f;
    if (c == 0) v = 1.0f;
    else if (c <= 17) v = state[(row0 + r) * 17 + (c - 1)];
    aL[r * LD1 + c] = (_Float16)v;
  }
  {
    int r = tid >> 3, c = tid & 7;          // 64 rows x 8 cols (tid < 512)
    aL[r * LD1 + 400 + c] = (c == 0) ? (_Float16)1.0f : (_Float16)0.0f;
  }
  if (tid < 16) aL[64 * LD1 + tid] = (_Float16)0.0f;
  __syncthreads();

  // ---- load S fragments (cols 0..31), then barrier before phase-1 overwrites ----
  half8 S[4];
#pragma unroll
  for (int m = 0; m < 4; ++m)
    S[m] = *reinterpret_cast<const half8*>(&aL[(16 * m + r15) * LD1 + 8 * c4]);
  __syncthreads();

  // ---- phase 1: a1 = relu([1,state] @ [b1|W1]^T) ----
  {
    const half8* W1f = reinterpret_cast<const half8*>(ws);
#pragma unroll
    for (int t = 0; t < 4; ++t) {
      int tn = w + 8 * t;
      if (tn < 25) {
        half8 aW = W1f[tn * 64 + lane];
        floatx4 acc[4];
#pragma unroll
        for (int m = 0; m < 4; ++m) {
          acc[m] = (floatx4){0.f, 0.f, 0.f, 0.f};
          MFMA32(aW, S[m], acc[m]);
        }
        int n0 = tn * 16 + 4 * c4;   // < 400
#pragma unroll
        for (int m = 0; m < 4; ++m) {
          half4 hv = pack4_relu(acc[m]);
          *reinterpret_cast<half4*>(&aL[(16 * m + r15) * LD1 + n0]) = hv;
        }
      }
    }
  }
  __syncthreads();

  // ---- phase 2: a2 = relu(a1 @ W2^T + b2); n-tiles {3,3,3,3,2,2,2,2} ----
  {
    const half8* W2f = reinterpret_cast<const half8*>(ws + 14336);
    const int nt = (w < 4) ? 3 : 2;
    const int tn0 = (w < 4) ? (w * 3) : (12 + (w - 4) * 2);
    floatx4 acc[4][3];
#pragma unroll
    for (int m = 0; m < 4; ++m)
#pragma unroll
      for (int t = 0; t < 3; ++t) acc[m][t] = (floatx4){0.f, 0.f, 0.f, 0.f};

    half8 bA[3];
#pragma unroll
    for (int t = 0; t < 3; ++t)
      if (t < nt) bA[t] = W2f[((tn0 + t) * 13 + 0) * 64 + lane];

#pragma unroll 1
    for (int ks = 0; ks < 13; ++ks) {
      half8 F[4];
#pragma unroll
      for (int m = 0; m < 4; ++m)
        F[m] = *reinterpret_cast<const half8*>(&aL[(16 * m + r15) * LD1 + ks * 32 + 8 * c4]);
      __builtin_amdgcn_s_setprio(1);
#pragma unroll
      for (int t = 0; t < 3; ++t)
        if (t < nt)
#pragma unroll
          for (int m = 0; m < 4; ++m)
            MFMA32(bA[t], F[m], acc[m][t]);
      __builtin_amdgcn_s_setprio(0);
      if (ks < 12) {
#pragma unroll
        for (int t = 0; t < 3; ++t)
          if (t < nt) bA[t] = W2f[((tn0 + t) * 13 + ks + 1) * 64 + lane];
      }
    }

    __syncthreads();  // all a1 reads complete before aliased a2 writes

    // epilogue: packed relu; n==300 forced 1.0 (b3 slot); n 301..319 write 0
#pragma unroll
    for (int t = 0; t < 3; ++t)
      if (t < nt) {
        int n0 = (tn0 + t) * 16 + 4 * c4;
#pragma unroll
        for (int m = 0; m < 4; ++m) {
          half4 hv = pack4_relu(acc[m][t]);
          if (n0 == 300) hv[0] = (_Float16)1.0f;
          *reinterpret_cast<half4*>(&aL[(16 * m + r15) * LD2 + n0]) = hv;
        }
      }
  }
  __syncthreads();

  // ---- phase 3+4: z3 = a2 @ W3^T + b3 -> tanh -> projection -> store; waves 0..3 ----
  if (w < 4) {
    const half8* W3f = reinterpret_cast<const half8*>(ws + 147456);
    floatx4 za = (floatx4){0.f, 0.f, 0.f, 0.f};
    floatx4 zb = (floatx4){0.f, 0.f, 0.f, 0.f};
    const int row = 16 * w + r15;
#pragma unroll
    for (int ks = 0; ks < 10; ks += 2) {
      half8 F0 = *reinterpret_cast<const half8*>(&aL[row * LD2 + ks * 32 + 8 * c4]);
      half8 F1 = *reinterpret_cast<const half8*>(&aL[row * LD2 + (ks + 1) * 32 + 8 * c4]);
      MFMA32(W3f[ks * 64 + lane], F0, za);
      MFMA32(W3f[(ks + 1) * 64 + lane], F1, zb);
    }
    floatx4 z = za + zb;
    // lane(c4,r15) holds n = 4*c4+j for act-row = 16w+r15. Owners: c4==0 lanes.
    float v4 = __shfl(z[0], r15 + 16, 64);  // n=4 from lane (c4=1, r15)
    float v5 = __shfl(z[1], r15 + 16, 64);  // n=5
    if (c4 == 0) {
      const int grow = row0 + row;
      float q[6], wv[6], aq[6], wa[6];
      q[0] = fast_tanh(z[0]); q[1] = fast_tanh(z[1]);
      q[2] = fast_tanh(z[2]); q[3] = fast_tanh(z[3]);
      q[4] = fast_tanh(v4);   q[5] = fast_tanh(v5);
      float S2 = 0.f;
#pragma unroll
      for (int i = 0; i < 6; ++i) {
        wv[i] = fabsf(state[grow * 17 + 11 + i]);
        aq[i] = fabsf(q[i]);
        wa[i] = wv[i] * aq[i];
        S2 += wa[i];
      }
      float lam = 0.f;
      if (!(S2 <= C_RADIUS)) {
        float rr[6], w2s[6], was[6];
#pragma unroll
        for (int i = 0; i < 6; ++i) {
          rr[i] = (wv[i] > 0.f) ? (aq[i] / fmaxf(wv[i], 1e-30f)) : -__builtin_inff();
          w2s[i] = wv[i] * wv[i];
          was[i] = wa[i];
        }
#pragma unroll
        for (int p = 0; p < 5; ++p)
#pragma unroll
          for (int j2 = 0; j2 < 5; ++j2)
            if (j2 < 5 - p) {
              if (rr[j2] < rr[j2 + 1]) {
                float t0 = rr[j2];  rr[j2] = rr[j2 + 1];  rr[j2 + 1] = t0;
                float t1 = w2s[j2]; w2s[j2] = w2s[j2 + 1]; w2s[j2 + 1] = t1;
                float t2 = was[j2]; was[j2] = was[j2 + 1]; was[j2 + 1] = t2;
              }
            }
        float A = 0.f, Bc = 0.f;
        float lamk[6];
        int kc = 0;
#pragma unroll
        for (int i = 0; i < 6; ++i) {
          A += was[i];
          Bc += w2s[i];
          lamk[i] = (A - C_RADIUS) / fmaxf(Bc, 1e-30f);
          if (rr[i] > lamk[i]) ++kc;
        }
        int idx = kc - 1;
        if (idx < 0) idx = 0;
        float lsel = lamk[0];
#pragma unroll
        for (int i = 1; i < 6; ++i)
          if (i == idx) lsel = lamk[i];
        lam = fmaxf(lsel, 0.f);
      }
#pragma unroll
      for (int i = 0; i < 6; ++i) {
        float x = fmaxf(aq[i] - lam * wv[i], 0.f);
        out[grow * 6 + i] = copysignf(x, q[i]);
      }
    }
  }
}

extern "C" void kernel_launch(void* const* d_in, const int* in_sizes, int n_in,
                              void* d_out, int out_size, void* d_ws, size_t ws_size,
                              hipStream_t stream) {
  const float* state = (const float*)d_in[0];
  const float* w1 = (const float*)d_in[1];
  const float* b1 = (const float*)d_in[2];
  const float* w2 = (const float*)d_in[3];
  const float* b2 = (const float*)d_in[4];
  const float* w3 = (const float*)d_in[5];
  const float* b3 = (const float*)d_in[6];
  _Float16* ws = (_Float16*)d_ws;
  float* out = (float*)d_out;

  actor_prep<<<75, 256, 0, stream>>>(w1, b1, w2, b2, w3, b3, ws);
  actor_fused<<<4096, 512, 0, stream>>>(state, ws, out);
}